// Round 3
// baseline (325.381 us; speedup 1.0000x reference)
//
#include <hip/hip_runtime.h>

// SioConvPS: z/dt/g projections (bf16 MFMA GEMM, m97 gload_lds structure)
// -> stable linear scan h_t = sig(z)sig(dt) + sig(-dt) h_{t-1} (chunked)
// -> gated y GEMM.  Outputs (f32): d_out = [y (B,L,D), h (B,L,D)].

#define BDIM 4
#define LDIM 4096
#define DDIM 1024
#define MROWS (BDIM * LDIM)   // 16384
#define KDIM 1024
#define NPROJ 3072
#define NCHUNK 64             // chunks along L
#define LCHUNK 64             // LDIM / NCHUNK

typedef __attribute__((ext_vector_type(8))) short short8v;
typedef __attribute__((ext_vector_type(4))) float f32x4;

__device__ __forceinline__ float bf2f(short u) {
    union { float f; unsigned int i; } v;
    v.i = ((unsigned int)(unsigned short)u) << 16;
    return v.f;
}
__device__ __forceinline__ short f2bf(float f) {
    union { float f; unsigned int i; } v; v.f = f;
    unsigned int r = v.i + 0x7FFFu + ((v.i >> 16) & 1u);  // RNE
    return (short)(r >> 16);
}
__device__ __forceinline__ float sigf(float x) { return 1.f / (1.f + __expf(-x)); }

// ---------------- cast f32 -> bf16, vectorized ----------------
__global__ void cast_f32_bf16(const float* __restrict__ src, short* __restrict__ dst, int n4) {
    int i = blockIdx.x * blockDim.x + threadIdx.x;
    int stride = gridDim.x * blockDim.x;
    for (; i < n4; i += stride) {
        float4 v = reinterpret_cast<const float4*>(src)[i];
        short4 o;
        o.x = f2bf(v.x); o.y = f2bf(v.y); o.z = f2bf(v.z); o.w = f2bf(v.w);
        reinterpret_cast<short4*>(dst)[i] = o;
    }
}

// ---------------- bf16 GEMM: C = A @ B^T (+bias) (*silu(gate)) ----------------
// A: MxK row-major bf16. Bm: NxK row-major bf16 (torch weight layout).
// C: MxN, bf16 or f32 per OUT_BF16. Optional gate (bf16, ld=ldg): C *= silu(gate).
// m97 structure: 128x128 tile, BK=64, 4 waves, global_load_lds width=16,
// linear LDS (gload_lds dest is wave-uniform+lane*16 -> no swizzle possible).
#define BM 128
#define BN 128
#define BK 64

template<int OUT_BF16, int HAS_GATE>
__global__ __launch_bounds__(256) void gemm_bt(
    const short* __restrict__ A, const short* __restrict__ Bm,
    const float* __restrict__ bias, void* __restrict__ Cv,
    int M, int N, int K,
    const short* __restrict__ gate, int ldg)
{
    __shared__ short lds_a[BM * BK];
    __shared__ short lds_b[BN * BK];

    const int tid  = threadIdx.x;
    const int lane = tid & 63;
    const int wid  = tid >> 6;
    const int wm   = wid >> 1;          // 0..1
    const int wn   = wid & 1;           // 0..1

    // XCD-aware bijective block swizzle (nwg % 8 == 0 in all our launches)
    const int gx   = gridDim.x;
    const int nwg  = gx * gridDim.y;
    int flat = blockIdx.y * gx + blockIdx.x;
    if ((nwg & 7) == 0) {
        int q = nwg >> 3;
        flat = (flat & 7) * q + (flat >> 3);
    }
    const int m0 = (flat / gx) * BM;
    const int n0 = (flat % gx) * BN;

    const int lrow = lane & 15;         // fragment row (A) / col (B/C)
    const int kq   = lane >> 4;         // k quarter 0..3

    f32x4 acc[4][4];
#pragma unroll
    for (int i = 0; i < 4; ++i)
#pragma unroll
        for (int j = 0; j < 4; ++j)
            acc[i][j] = (f32x4){0.f, 0.f, 0.f, 0.f};

    for (int k0 = 0; k0 < K; k0 += BK) {
        // stage A,B tiles via global_load_lds (16B/lane, linear LDS)
#pragma unroll
        for (int i = 0; i < 4; ++i) {
            int chunk = i * 256 + tid;       // 0..1023 chunks of 16B
            int row   = chunk >> 3;          // 0..127
            int col16 = chunk & 7;
            int ldsoff = (i * 256 + wid * 64) * 8;   // wave-uniform, shorts
            __builtin_amdgcn_global_load_lds(
                (const __attribute__((address_space(1))) void*)
                    (A + (size_t)(m0 + row) * K + k0 + col16 * 8),
                (__attribute__((address_space(3))) void*)(&lds_a[ldsoff]),
                16, 0, 0);
            __builtin_amdgcn_global_load_lds(
                (const __attribute__((address_space(1))) void*)
                    (Bm + (size_t)(n0 + row) * K + k0 + col16 * 8),
                (__attribute__((address_space(3))) void*)(&lds_b[ldsoff]),
                16, 0, 0);
        }
        __syncthreads();

#pragma unroll
        for (int kk = 0; kk < 2; ++kk) {
            short8v af[4], bfrag[4];
            int c16 = kk * 4 + kq;
#pragma unroll
            for (int mi = 0; mi < 4; ++mi) {
                int row = wm * 64 + mi * 16 + lrow;
                af[mi] = *reinterpret_cast<const short8v*>(
                    &lds_a[row * BK + c16 * 8]);
            }
#pragma unroll
            for (int ni = 0; ni < 4; ++ni) {
                int row = wn * 64 + ni * 16 + lrow;
                bfrag[ni] = *reinterpret_cast<const short8v*>(
                    &lds_b[row * BK + c16 * 8]);
            }
#pragma unroll
            for (int mi = 0; mi < 4; ++mi)
#pragma unroll
                for (int ni = 0; ni < 4; ++ni)
                    acc[mi][ni] = __builtin_amdgcn_mfma_f32_16x16x32_bf16(
                        af[mi], bfrag[ni], acc[mi][ni], 0, 0, 0);
        }
        __syncthreads();
    }

    // epilogue: C/D layout col=lane&15, row=(lane>>4)*4+reg  [verified m89/m91]
    const int lr4 = (lane >> 4) * 4;
#pragma unroll
    for (int mi = 0; mi < 4; ++mi) {
        int rowb = m0 + wm * 64 + mi * 16 + lr4;
#pragma unroll
        for (int ni = 0; ni < 4; ++ni) {
            int col = n0 + wn * 64 + ni * 16 + lrow;
            float bv = bias[col];
#pragma unroll
            for (int r = 0; r < 4; ++r) {
                int row = rowb + r;
                float val = acc[mi][ni][r] + bv;
                if (HAS_GATE) {
                    float g = bf2f(gate[(size_t)row * ldg + col]);
                    val *= g * sigf(g);
                }
                if (OUT_BF16)
                    ((short*)Cv)[(size_t)row * N + col] = f2bf(val);
                else
                    ((float*)Cv)[(size_t)row * N + col] = val;
            }
        }
    }
}

// ---------------- scan pass 1: per-chunk (A = prod oda, Bv = local h, h_init=0) ----------------
__global__ __launch_bounds__(1024) void chunk_reduce(
    const short* __restrict__ pre, float* __restrict__ sA, float* __restrict__ sBv)
{
    const int d = threadIdx.x;
    const int c = blockIdx.x;
    const int b = blockIdx.y;
    float Aacc = 1.f, Bacc = 0.f;
    size_t base = ((size_t)(b * LDIM) + c * LCHUNK) * NPROJ;
    for (int i = 0; i < LCHUNK; ++i) {
        float z  = bf2f(pre[base + d]);
        float dt = bf2f(pre[base + DDIM + d]);
        float e  = __expf(-dt);
        float r  = 1.f / (1.f + e);     // sig(dt)
        float oda = e * r;              // sig(-dt)
        float zda = sigf(z) * r;        // sig(z)*sig(dt)
        Bacc = zda + oda * Bacc;
        Aacc *= oda;
        base += NPROJ;
    }
    int idx = ((b * NCHUNK + c) << 10) + d;
    sA[idx]  = Aacc;
    sBv[idx] = Bacc;
}

// ---------------- scan pass 2: sequential prefix over chunks, record per-chunk h_init ----------------
__global__ __launch_bounds__(1024) void chunk_prefix(
    const float* __restrict__ sA, const float* __restrict__ sBv,
    const float* __restrict__ hidden, float* __restrict__ sI)
{
    const int d = threadIdx.x;
    const int b = blockIdx.x;
    float h = hidden[b * DDIM + d];
    for (int c = 0; c < NCHUNK; ++c) {
        int idx = ((b * NCHUNK + c) << 10) + d;
        sI[idx] = h;
        h = sBv[idx] + sA[idx] * h;
    }
}

// ---------------- scan pass 3: recompute with h_init; write h f32 (d_out) + bf16 (for y-GEMM) ----------------
__global__ __launch_bounds__(1024) void chunk_apply(
    const short* __restrict__ pre, const float* __restrict__ sI,
    float* __restrict__ hout, short* __restrict__ hbf)
{
    const int d = threadIdx.x;
    const int c = blockIdx.x;
    const int b = blockIdx.y;
    float h = sI[((b * NCHUNK + c) << 10) + d];
    size_t base  = ((size_t)(b * LDIM) + c * LCHUNK) * NPROJ;
    size_t obase = ((size_t)(b * LDIM) + c * LCHUNK) * DDIM + d;
    for (int i = 0; i < LCHUNK; ++i) {
        float z  = bf2f(pre[base + d]);
        float dt = bf2f(pre[base + DDIM + d]);
        float e  = __expf(-dt);
        float r  = 1.f / (1.f + e);
        float oda = e * r;
        float zda = sigf(z) * r;
        h = zda + oda * h;
        hout[obase] = h;
        hbf[obase]  = f2bf(h);
        base += NPROJ;
        obase += DDIM;
    }
}

extern "C" void kernel_launch(void* const* d_in, const int* in_sizes, int n_in,
                              void* d_out, int out_size, void* d_ws, size_t ws_size,
                              hipStream_t stream) {
    const float* x      = (const float*)d_in[0];
    const float* hidden = (const float*)d_in[1];
    const float* W_ln_z = (const float*)d_in[2];
    const float* b_ln_z = (const float*)d_in[3];
    const float* W_dt   = (const float*)d_in[4];
    const float* b_dt   = (const float*)d_in[5];
    const float* W_y    = (const float*)d_in[6];
    const float* b_y    = (const float*)d_in[7];
    const float* W_g    = (const float*)d_in[8];
    const float* b_g    = (const float*)d_in[9];

    char* ws = (char*)d_ws;
    // ws layout (bytes)
    short* x_bf   = (short*)(ws + 0);                       // 33,554,432 (reused as h_bf after proj GEMM)
    short* Wcat   = (short*)(ws + 33554432);                //  6,291,456 (W_ln_z|W_dt|W_g)
    short* Wy_bf  = (short*)(ws + 39845888);                //  2,097,152
    float* biascat= (float*)(ws + 41943040);                //     12,288
    short* pre    = (short*)(ws + 41955328);                // 100,663,296 (M x 3072 bf16)
    float* sA     = (float*)(ws + 142618624);               //  1,048,576
    float* sBv    = (float*)(ws + 143667200);               //  1,048,576
    float* sI     = (float*)(ws + 144715776);               //  1,048,576
    // total ~139 MB

    // 1) casts
    cast_f32_bf16<<<2048, 256, 0, stream>>>(x, x_bf, (MROWS * KDIM) / 4);
    cast_f32_bf16<<<1024, 256, 0, stream>>>(W_ln_z, Wcat,                (DDIM * KDIM) / 4);
    cast_f32_bf16<<<1024, 256, 0, stream>>>(W_dt,   Wcat + DDIM * KDIM,  (DDIM * KDIM) / 4);
    cast_f32_bf16<<<1024, 256, 0, stream>>>(W_g,    Wcat + 2 * DDIM * KDIM, (DDIM * KDIM) / 4);
    cast_f32_bf16<<<1024, 256, 0, stream>>>(W_y,    Wy_bf,               (DDIM * KDIM) / 4);

    // 2) concatenated bias (f32)
    hipMemcpyAsync(biascat,            b_ln_z, DDIM * sizeof(float), hipMemcpyDeviceToDevice, stream);
    hipMemcpyAsync(biascat + DDIM,     b_dt,   DDIM * sizeof(float), hipMemcpyDeviceToDevice, stream);
    hipMemcpyAsync(biascat + 2 * DDIM, b_g,    DDIM * sizeof(float), hipMemcpyDeviceToDevice, stream);

    // 3) fused projection GEMM: pre[M x 3072] = x @ [W_ln_z|W_dt|W_g]^T + bias (bf16 out)
    gemm_bt<1, 0><<<dim3(NPROJ / BN, MROWS / BM), 256, 0, stream>>>(
        x_bf, Wcat, biascat, pre, MROWS, NPROJ, KDIM, nullptr, 0);

    // 4) chunked scan -> h: f32 into d_out second half, bf16 into x_bf (reuse)
    float* y_out = (float*)d_out;
    float* h_out = (float*)d_out + (size_t)MROWS * DDIM;
    short* h_bf  = x_bf;
    chunk_reduce<<<dim3(NCHUNK, BDIM), 1024, 0, stream>>>(pre, sA, sBv);
    chunk_prefix<<<dim3(BDIM), 1024, 0, stream>>>(sA, sBv, hidden, sI);
    chunk_apply<<<dim3(NCHUNK, BDIM), 1024, 0, stream>>>(pre, sI, h_out, h_bf);

    // 5) gated output GEMM (f32 out): y = (h @ W_y^T + b_y) * silu(g_pre)
    gemm_bt<0, 1><<<dim3(DDIM / BN, MROWS / BM), 256, 0, stream>>>(
        h_bf, Wy_bf, b_y, y_out, MROWS, DDIM, KDIM, pre + 2 * DDIM, NPROJ);
}

// Round 4
// 285.533 us; speedup vs baseline: 1.1396x; 1.1396x over previous
//
#include <hip/hip_runtime.h>

// SioConvPS: z/dt/g projections (bf16 MFMA GEMM, 256^2 8-phase counted-vmcnt)
// -> stable linear scan h_t = sig(z)sig(dt) + sig(-dt) h_{t-1} (chunked)
// -> gated y GEMM.  Outputs (f32): d_out = [y (B,L,D), h (B,L,D)].

#define BDIM 4
#define LDIM 4096
#define DDIM 1024
#define MROWS (BDIM * LDIM)   // 16384
#define KDIM 1024
#define NPROJ 3072
#define NCHUNK 64             // chunks along L
#define LCHUNK 64             // LDIM / NCHUNK

typedef __attribute__((ext_vector_type(8))) short short8v;
typedef __attribute__((ext_vector_type(4))) float f32x4;

__device__ __forceinline__ float bf2f(short u) {
    union { float f; unsigned int i; } v;
    v.i = ((unsigned int)(unsigned short)u) << 16;
    return v.f;
}
__device__ __forceinline__ short f2bf(float f) {
    union { float f; unsigned int i; } v; v.f = f;
    unsigned int r = v.i + 0x7FFFu + ((v.i >> 16) & 1u);  // RNE
    return (short)(r >> 16);
}
__device__ __forceinline__ float sigf(float x) { return 1.f / (1.f + __expf(-x)); }

// ---------------- cast f32 -> bf16, vectorized ----------------
__global__ void cast_f32_bf16(const float* __restrict__ src, short* __restrict__ dst, int n4) {
    int i = blockIdx.x * blockDim.x + threadIdx.x;
    int stride = gridDim.x * blockDim.x;
    for (; i < n4; i += stride) {
        float4 v = reinterpret_cast<const float4*>(src)[i];
        short4 o;
        o.x = f2bf(v.x); o.y = f2bf(v.y); o.z = f2bf(v.z); o.w = f2bf(v.w);
        reinterpret_cast<short4*>(dst)[i] = o;
    }
}

// ================= 256x256 8-phase bf16 GEMM: C = A @ B^T (+bias)(*silu(gate)) ===========
// A: MxK row-major bf16. Bm: NxK row-major bf16. K multiple of 128, M,N multiples of 256.
// 512 threads = 8 waves (2M x 4N, 16-row interleaved). BK=64, 2 K-tiles per iteration,
// 8 phases/iter, half-tile staging via global_load_lds (pre-swizzled global source),
// counted vmcnt(4) at end of P4/P8 only.

// stage one half-tile (128 rows x 64 k) of tile at k-offset `kofs` into buffer `bufi`
#define STAGE(ldsarr, bufi, half, gbase, kofs)                                     \
  do {                                                                             \
    _Pragma("unroll")                                                              \
    for (int _i = 0; _i < 2; ++_i) {                                               \
      int _c = _i * 512 + tid;                                                     \
      int _row = _c >> 3, _g = _c & 7;                                             \
      int _gsw = _g ^ (_row & 7);                                                  \
      __builtin_amdgcn_global_load_lds(                                            \
        (const __attribute__((address_space(1))) void*)(                           \
            (gbase) + (size_t)((half) * 128 + _row) * K + (kofs) + _gsw * 8),      \
        (__attribute__((address_space(3))) void*)(                                 \
            &ldsarr[bufi][(half) * 8192 + (_i * 512 + wid * 64) * 8]),             \
        16, 0, 0);                                                                 \
    }                                                                              \
  } while (0)

// phase begin: 12 ds_read_b128 (quadrant mh,nh of buffer bufi)
#define PH_BEGIN(bufi, mh, nh)                                                     \
  {                                                                                \
    short8v _af[4][2], _bfv[2][2];                                                 \
    _Pragma("unroll")                                                              \
    for (int _m = 0; _m < 4; ++_m) {                                               \
      int _r = ((mh) * 4 + _m) * 32 + wm * 16 + lrow;                              \
      _Pragma("unroll")                                                            \
      for (int _kk = 0; _kk < 2; ++_kk) {                                          \
        int _gsw = ((_kk * 4 + kq) ^ (lrow & 7)) * 8;                              \
        _af[_m][_kk] = *(const short8v*)&lds_a[bufi][_r * 64 + _gsw];              \
      }                                                                            \
    }                                                                              \
    _Pragma("unroll")                                                              \
    for (int _n = 0; _n < 2; ++_n) {                                               \
      int _r = ((nh) * 2 + _n) * 64 + wn * 16 + lrow;                              \
      _Pragma("unroll")                                                            \
      for (int _kk = 0; _kk < 2; ++_kk) {                                          \
        int _gsw = ((_kk * 4 + kq) ^ (lrow & 7)) * 8;                              \
        _bfv[_n][_kk] = *(const short8v*)&lds_b[bufi][_r * 64 + _gsw];             \
      }                                                                            \
    }

// phase end: barrier, prio-wrapped 16 MFMA
#define PH_END(mh, nh)                                                             \
    asm volatile("s_barrier" ::: "memory");                                        \
    __builtin_amdgcn_s_setprio(1);                                                 \
    _Pragma("unroll")                                                              \
    for (int _kk = 0; _kk < 2; ++_kk)                                              \
      _Pragma("unroll")                                                            \
      for (int _m = 0; _m < 4; ++_m)                                               \
        _Pragma("unroll")                                                          \
        for (int _n = 0; _n < 2; ++_n)                                             \
          acc[(mh) * 4 + _m][(nh) * 2 + _n] =                                      \
              __builtin_amdgcn_mfma_f32_16x16x32_bf16(                             \
                  _af[_m][_kk], _bfv[_n][_kk],                                     \
                  acc[(mh) * 4 + _m][(nh) * 2 + _n], 0, 0, 0);                     \
    __builtin_amdgcn_s_setprio(0);                                                 \
  }

#define BAR_PLAIN()  asm volatile("s_barrier" ::: "memory")
#define BAR_VM4()    asm volatile("s_waitcnt vmcnt(4)\ns_barrier" ::: "memory")
#define BAR_VM0()    asm volatile("s_waitcnt vmcnt(0)\ns_barrier" ::: "memory")

template<int OUT_BF16, int HAS_GATE>
__global__ __launch_bounds__(512, 2) void gemm256(
    const short* __restrict__ A, const short* __restrict__ Bm,
    const float* __restrict__ bias, void* __restrict__ Cv,
    int M, int N, int K,
    const short* __restrict__ gate, int ldg)
{
    __shared__ short lds_a[2][16384];   // [buf][256 rows x 64 k], 32KB each
    __shared__ short lds_b[2][16384];

    const int tid  = threadIdx.x;
    const int lane = tid & 63;
    const int wid  = tid >> 6;          // 0..7
    const int wm   = wid >> 2;          // 0..1  (M interleave at 16 rows)
    const int wn   = wid & 3;           // 0..3  (N interleave at 16 cols)
    const int lrow = lane & 15;
    const int kq   = lane >> 4;

    // XCD-aware bijective block swizzle (all our grids are %8==0)
    const int gx  = gridDim.x;
    const int nwg = gx * gridDim.y;
    int flat = blockIdx.y * gx + blockIdx.x;
    if ((nwg & 7) == 0) { int q = nwg >> 3; flat = (flat & 7) * q + (flat >> 3); }
    const int m0 = (flat / gx) * 256;
    const int n0 = (flat % gx) * 256;

    const short* Abase = A + (size_t)m0 * K;
    const short* Bbase = Bm + (size_t)n0 * K;

    f32x4 acc[8][4];
#pragma unroll
    for (int i = 0; i < 8; ++i)
#pragma unroll
        for (int j = 0; j < 4; ++j)
            acc[i][j] = (f32x4){0.f, 0.f, 0.f, 0.f};

    // prologue: tile0 all 4 halves + tile1 A0,B0 (12 loads); land tile0, keep 4 in flight
    STAGE(lds_a, 0, 0, Abase, 0);
    STAGE(lds_a, 0, 1, Abase, 0);
    STAGE(lds_b, 0, 0, Bbase, 0);
    STAGE(lds_b, 0, 1, Bbase, 0);
    STAGE(lds_a, 1, 0, Abase, 64);
    STAGE(lds_b, 1, 0, Bbase, 64);
    BAR_VM4();

    const int NT = K / 64;              // even, >= 4
    for (int t = 0; t < NT; t += 2) {
        const int k1 = (t + 1) * 64, k2 = (t + 2) * 64, k3 = (t + 3) * 64;
        const bool more = (t + 2) < NT;

        PH_BEGIN(0, 0, 0)  STAGE(lds_a, 1, 1, Abase, k1);              PH_END(0, 0)  BAR_PLAIN();
        PH_BEGIN(0, 0, 1)  STAGE(lds_b, 1, 1, Bbase, k1);              PH_END(0, 1)  BAR_PLAIN();
        PH_BEGIN(0, 1, 0)  if (more) STAGE(lds_a, 0, 0, Abase, k2);    PH_END(1, 0)  BAR_PLAIN();
        PH_BEGIN(0, 1, 1)  if (more) STAGE(lds_b, 0, 0, Bbase, k2);    PH_END(1, 1)
        if (more) { BAR_VM4(); } else { BAR_VM0(); }

        PH_BEGIN(1, 0, 0)  if (more) STAGE(lds_a, 0, 1, Abase, k2);    PH_END(0, 0)  BAR_PLAIN();
        PH_BEGIN(1, 0, 1)  if (more) STAGE(lds_b, 0, 1, Bbase, k2);    PH_END(0, 1)  BAR_PLAIN();
        PH_BEGIN(1, 1, 0)  if (more) STAGE(lds_a, 1, 0, Abase, k3);    PH_END(1, 0)  BAR_PLAIN();
        PH_BEGIN(1, 1, 1)  if (more) STAGE(lds_b, 1, 0, Bbase, k3);    PH_END(1, 1)
        if (more) { BAR_VM4(); } else { BAR_PLAIN(); }
    }

    // epilogue: C/D layout col=lane&15, row=(lane>>4)*4+reg  [verified r2]
    const int lr4 = (lane >> 4) * 4;
#pragma unroll
    for (int mi = 0; mi < 8; ++mi) {
        int rowb = m0 + mi * 32 + wm * 16 + lr4;
#pragma unroll
        for (int ni = 0; ni < 4; ++ni) {
            int col = n0 + ni * 64 + wn * 16 + lrow;
            float bv = bias[col];
#pragma unroll
            for (int r = 0; r < 4; ++r) {
                int row = rowb + r;
                float val = acc[mi][ni][r] + bv;
                if (HAS_GATE) {
                    float g = bf2f(gate[(size_t)row * ldg + col]);
                    val *= g * sigf(g);
                }
                if (OUT_BF16)
                    ((short*)Cv)[(size_t)row * N + col] = f2bf(val);
                else
                    ((float*)Cv)[(size_t)row * N + col] = val;
            }
        }
    }
}

// ---------------- scan pass 1: per-chunk (A = prod oda, Bv = local h, h_init=0) ----------------
__global__ __launch_bounds__(1024) void chunk_reduce(
    const short* __restrict__ pre, float* __restrict__ sA, float* __restrict__ sBv)
{
    const int d = threadIdx.x;
    const int c = blockIdx.x;
    const int b = blockIdx.y;
    float Aacc = 1.f, Bacc = 0.f;
    size_t base = ((size_t)(b * LDIM) + c * LCHUNK) * NPROJ;
    for (int i = 0; i < LCHUNK; ++i) {
        float z  = bf2f(pre[base + d]);
        float dt = bf2f(pre[base + DDIM + d]);
        float e  = __expf(-dt);
        float r  = 1.f / (1.f + e);     // sig(dt)
        float oda = e * r;              // sig(-dt)
        float zda = sigf(z) * r;        // sig(z)*sig(dt)
        Bacc = zda + oda * Bacc;
        Aacc *= oda;
        base += NPROJ;
    }
    int idx = ((b * NCHUNK + c) << 10) + d;
    sA[idx]  = Aacc;
    sBv[idx] = Bacc;
}

// ---------------- scan pass 2: sequential prefix over chunks, record per-chunk h_init ----------------
__global__ __launch_bounds__(1024) void chunk_prefix(
    const float* __restrict__ sA, const float* __restrict__ sBv,
    const float* __restrict__ hidden, float* __restrict__ sI)
{
    const int d = threadIdx.x;
    const int b = blockIdx.x;
    float h = hidden[b * DDIM + d];
    for (int c = 0; c < NCHUNK; ++c) {
        int idx = ((b * NCHUNK + c) << 10) + d;
        sI[idx] = h;
        h = sBv[idx] + sA[idx] * h;
    }
}

// ---------------- scan pass 3: recompute with h_init; write h f32 (d_out) + bf16 (for y-GEMM) ----------------
__global__ __launch_bounds__(1024) void chunk_apply(
    const short* __restrict__ pre, const float* __restrict__ sI,
    float* __restrict__ hout, short* __restrict__ hbf)
{
    const int d = threadIdx.x;
    const int c = blockIdx.x;
    const int b = blockIdx.y;
    float h = sI[((b * NCHUNK + c) << 10) + d];
    size_t base  = ((size_t)(b * LDIM) + c * LCHUNK) * NPROJ;
    size_t obase = ((size_t)(b * LDIM) + c * LCHUNK) * DDIM + d;
    for (int i = 0; i < LCHUNK; ++i) {
        float z  = bf2f(pre[base + d]);
        float dt = bf2f(pre[base + DDIM + d]);
        float e  = __expf(-dt);
        float r  = 1.f / (1.f + e);
        float oda = e * r;
        float zda = sigf(z) * r;
        h = zda + oda * h;
        hout[obase] = h;
        hbf[obase]  = f2bf(h);
        base += NPROJ;
        obase += DDIM;
    }
}

extern "C" void kernel_launch(void* const* d_in, const int* in_sizes, int n_in,
                              void* d_out, int out_size, void* d_ws, size_t ws_size,
                              hipStream_t stream) {
    const float* x      = (const float*)d_in[0];
    const float* hidden = (const float*)d_in[1];
    const float* W_ln_z = (const float*)d_in[2];
    const float* b_ln_z = (const float*)d_in[3];
    const float* W_dt   = (const float*)d_in[4];
    const float* b_dt   = (const float*)d_in[5];
    const float* W_y    = (const float*)d_in[6];
    const float* b_y    = (const float*)d_in[7];
    const float* W_g    = (const float*)d_in[8];
    const float* b_g    = (const float*)d_in[9];

    char* ws = (char*)d_ws;
    // ws layout (bytes)
    short* x_bf   = (short*)(ws + 0);                       // 33,554,432 (reused as h_bf after proj GEMM)
    short* Wcat   = (short*)(ws + 33554432);                //  6,291,456 (W_ln_z|W_dt|W_g)
    short* Wy_bf  = (short*)(ws + 39845888);                //  2,097,152
    float* biascat= (float*)(ws + 41943040);                //     12,288
    short* pre    = (short*)(ws + 41955328);                // 100,663,296 (M x 3072 bf16)
    float* sA     = (float*)(ws + 142618624);               //  1,048,576
    float* sBv    = (float*)(ws + 143667200);               //  1,048,576
    float* sI     = (float*)(ws + 144715776);               //  1,048,576
    // total ~139 MB

    // 1) casts
    cast_f32_bf16<<<2048, 256, 0, stream>>>(x, x_bf, (MROWS * KDIM) / 4);
    cast_f32_bf16<<<1024, 256, 0, stream>>>(W_ln_z, Wcat,                (DDIM * KDIM) / 4);
    cast_f32_bf16<<<1024, 256, 0, stream>>>(W_dt,   Wcat + DDIM * KDIM,  (DDIM * KDIM) / 4);
    cast_f32_bf16<<<1024, 256, 0, stream>>>(W_g,    Wcat + 2 * DDIM * KDIM, (DDIM * KDIM) / 4);
    cast_f32_bf16<<<1024, 256, 0, stream>>>(W_y,    Wy_bf,               (DDIM * KDIM) / 4);

    // 2) concatenated bias (f32)
    hipMemcpyAsync(biascat,            b_ln_z, DDIM * sizeof(float), hipMemcpyDeviceToDevice, stream);
    hipMemcpyAsync(biascat + DDIM,     b_dt,   DDIM * sizeof(float), hipMemcpyDeviceToDevice, stream);
    hipMemcpyAsync(biascat + 2 * DDIM, b_g,    DDIM * sizeof(float), hipMemcpyDeviceToDevice, stream);

    // 3) fused projection GEMM: pre[M x 3072] = x @ [W_ln_z|W_dt|W_g]^T + bias (bf16 out)
    gemm256<1, 0><<<dim3(NPROJ / 256, MROWS / 256), 512, 0, stream>>>(
        x_bf, Wcat, biascat, pre, MROWS, NPROJ, KDIM, nullptr, 0);

    // 4) chunked scan -> h: f32 into d_out second half, bf16 into x_bf (reuse)
    float* y_out = (float*)d_out;
    float* h_out = (float*)d_out + (size_t)MROWS * DDIM;
    short* h_bf  = x_bf;
    chunk_reduce<<<dim3(NCHUNK, BDIM), 1024, 0, stream>>>(pre, sA, sBv);
    chunk_prefix<<<dim3(BDIM), 1024, 0, stream>>>(sA, sBv, hidden, sI);
    chunk_apply<<<dim3(NCHUNK, BDIM), 1024, 0, stream>>>(pre, sI, h_out, h_bf);

    // 5) gated output GEMM (f32 out): y = (h @ W_y^T + b_y) * silu(g_pre)
    gemm256<0, 1><<<dim3(DDIM / 256, MROWS / 256), 512, 0, stream>>>(
        h_bf, Wy_bf, b_y, y_out, MROWS, DDIM, KDIM, pre + 2 * DDIM, NPROJ);
}

// Round 5
// 263.101 us; speedup vs baseline: 1.2367x; 1.0853x over previous
//
#include <hip/hip_runtime.h>

// SioConvPS: z/dt/g projections (bf16 MFMA GEMM, 256^2 8-phase counted-vmcnt,
// single-read register subtiles) -> stable linear scan -> gated y GEMM.
// Outputs (f32): d_out = [y (B,L,D), h (B,L,D)].

#define BDIM 4
#define LDIM 4096
#define DDIM 1024
#define MROWS (BDIM * LDIM)   // 16384
#define KDIM 1024
#define NPROJ 3072
#define NCHUNK 64             // chunks along L
#define LCHUNK 64             // LDIM / NCHUNK

typedef __attribute__((ext_vector_type(8))) short short8v;
typedef __attribute__((ext_vector_type(4))) float f32x4;

__device__ __forceinline__ float bf2f(short u) {
    union { float f; unsigned int i; } v;
    v.i = ((unsigned int)(unsigned short)u) << 16;
    return v.f;
}
__device__ __forceinline__ short f2bf(float f) {
    union { float f; unsigned int i; } v; v.f = f;
    unsigned int r = v.i + 0x7FFFu + ((v.i >> 16) & 1u);  // RNE
    return (short)(r >> 16);
}
__device__ __forceinline__ float sigf(float x) { return 1.f / (1.f + __expf(-x)); }

// ---------------- cast f32 -> bf16, vectorized ----------------
__global__ void cast_f32_bf16(const float* __restrict__ src, short* __restrict__ dst, int n4) {
    int i = blockIdx.x * blockDim.x + threadIdx.x;
    int stride = gridDim.x * blockDim.x;
    for (; i < n4; i += stride) {
        float4 v = reinterpret_cast<const float4*>(src)[i];
        short4 o;
        o.x = f2bf(v.x); o.y = f2bf(v.y); o.z = f2bf(v.z); o.w = f2bf(v.w);
        reinterpret_cast<short4*>(dst)[i] = o;
    }
}

// ================= 256x256 8-phase bf16 GEMM: C = A @ B^T (+bias)(*silu(gate)) ===========
// 512 threads = 8 waves (2M x 4N, 16-row interleave). BK=64, 2 K-tiles/iter, 8 phases,
// half-tile staging via global_load_lds (pre-swizzled source), vmcnt(4) at P4/P8 only.
// Each fragment ds_read ONCE per K-tile; quadrant snake Q00->Q01->Q11->Q10 reuses regs.

#define STAGE(ldsarr, bufi, half, gbase, kofs)                                     \
  do {                                                                             \
    _Pragma("unroll")                                                              \
    for (int _i = 0; _i < 2; ++_i) {                                               \
      int _c = _i * 512 + tid;                                                     \
      int _row = _c >> 3, _g = _c & 7;                                             \
      int _gsw = _g ^ (_row & 7);                                                  \
      __builtin_amdgcn_global_load_lds(                                            \
        (const __attribute__((address_space(1))) void*)(                           \
            (gbase) + (size_t)((half) * 128 + _row) * K + (kofs) + _gsw * 8),      \
        (__attribute__((address_space(3))) void*)(                                 \
            &ldsarr[bufi][(half) * 8192 + (_i * 512 + wid * 64) * 8]),             \
        16, 0, 0);                                                                 \
    }                                                                              \
  } while (0)

// read 4 A m-frags (mi0..mi0+3), both k-halves, from buffer bufi
#define LDA4(dst, bufi, mi0)                                                       \
  _Pragma("unroll")                                                                \
  for (int _m = 0; _m < 4; ++_m) {                                                 \
    int _r = ((mi0) + _m) * 32 + wm * 16 + lrow;                                   \
    _Pragma("unroll")                                                              \
    for (int _kk = 0; _kk < 2; ++_kk)                                              \
      dst[_m][_kk] = *(const short8v*)&lds_a[bufi][_r * 64 +                       \
                       (((_kk * 4 + kq) ^ (lrow & 7)) * 8)];                       \
  }

// read 2 B n-frags (ni0..ni0+1), both k-halves, from buffer bufi
#define LDB2(dst, bufi, ni0)                                                       \
  _Pragma("unroll")                                                                \
  for (int _n = 0; _n < 2; ++_n) {                                                 \
    int _r = ((ni0) + _n) * 64 + wn * 16 + lrow;                                   \
    _Pragma("unroll")                                                              \
    for (int _kk = 0; _kk < 2; ++_kk)                                              \
      dst[_n][_kk] = *(const short8v*)&lds_b[bufi][_r * 64 +                       \
                       (((_kk * 4 + kq) ^ (lrow & 7)) * 8)];                       \
  }

// one C-quadrant x K=64: 16 MFMA, prio-wrapped
#define MFMAQ(mi0, ni0, afr, bfr)                                                  \
  __builtin_amdgcn_s_setprio(1);                                                   \
  _Pragma("unroll")                                                                \
  for (int _kk = 0; _kk < 2; ++_kk)                                                \
    _Pragma("unroll")                                                              \
    for (int _m = 0; _m < 4; ++_m)                                                 \
      _Pragma("unroll")                                                            \
      for (int _n = 0; _n < 2; ++_n)                                               \
        acc[(mi0) + _m][(ni0) + _n] = __builtin_amdgcn_mfma_f32_16x16x32_bf16(     \
            afr[_m][_kk], bfr[_n][_kk], acc[(mi0) + _m][(ni0) + _n], 0, 0, 0);     \
  __builtin_amdgcn_s_setprio(0);

#define BAR_PLAIN()  asm volatile("s_barrier" ::: "memory")
#define BAR_VM4()    asm volatile("s_waitcnt vmcnt(4)\ns_barrier" ::: "memory")
#define BAR_VM0()    asm volatile("s_waitcnt vmcnt(0)\ns_barrier" ::: "memory")

template<int OUT_BF16, int HAS_GATE>
__global__ __launch_bounds__(512, 2) void gemm256(
    const short* __restrict__ A, const short* __restrict__ Bm,
    const float* __restrict__ bias, void* __restrict__ Cv,
    int M, int N, int K,
    const short* __restrict__ gate, int ldg)
{
    __shared__ short lds_a[2][16384];   // [buf][256 rows x 64 k], 32KB each
    __shared__ short lds_b[2][16384];

    const int tid  = threadIdx.x;
    const int lane = tid & 63;
    const int wid  = tid >> 6;          // 0..7
    const int wm   = wid >> 2;          // 0..1  (M interleave at 16 rows)
    const int wn   = wid & 3;           // 0..3  (N interleave at 16 cols)
    const int lrow = lane & 15;
    const int kq   = lane >> 4;

    // XCD-aware bijective block swizzle (all our grids are %8==0)
    const int gx  = gridDim.x;
    const int nwg = gx * gridDim.y;
    int flat = blockIdx.y * gx + blockIdx.x;
    if ((nwg & 7) == 0) { int q = nwg >> 3; flat = (flat & 7) * q + (flat >> 3); }
    const int m0 = (flat / gx) * 256;
    const int n0 = (flat % gx) * 256;

    const short* Abase = A + (size_t)m0 * K;
    const short* Bbase = Bm + (size_t)n0 * K;

    f32x4 acc[8][4];
#pragma unroll
    for (int i = 0; i < 8; ++i)
#pragma unroll
        for (int j = 0; j < 4; ++j)
            acc[i][j] = (f32x4){0.f, 0.f, 0.f, 0.f};

    // prologue: tile0 all 4 halves + tile1 A0,B0 (12 loads); land tile0, keep 4 in flight
    STAGE(lds_a, 0, 0, Abase, 0);
    STAGE(lds_a, 0, 1, Abase, 0);
    STAGE(lds_b, 0, 0, Bbase, 0);
    STAGE(lds_b, 0, 1, Bbase, 0);
    STAGE(lds_a, 1, 0, Abase, 64);
    STAGE(lds_b, 1, 0, Bbase, 64);
    BAR_VM4();

    const int NT = K / 64;              // even, >= 4
    for (int t = 0; t < NT; t += 2) {
        const int k1 = (t + 1) * 64, k2 = (t + 2) * 64, k3 = (t + 3) * 64;
        const bool more = (t + 2) < NT;
        short8v af[4][2], b0[2][2], b1[2][2];

        // ---- K-tile 0 (buf 0) ----
        LDA4(af, 0, 0) LDB2(b0, 0, 0)
        STAGE(lds_a, 1, 1, Abase, k1);
        BAR_PLAIN(); MFMAQ(0, 0, af, b0) BAR_PLAIN();

        LDB2(b1, 0, 2)
        STAGE(lds_b, 1, 1, Bbase, k1);
        BAR_PLAIN(); MFMAQ(0, 2, af, b1) BAR_PLAIN();

        LDA4(af, 0, 4)
        if (more) STAGE(lds_a, 0, 0, Abase, k2);
        BAR_PLAIN(); MFMAQ(4, 2, af, b1) BAR_PLAIN();

        if (more) STAGE(lds_b, 0, 0, Bbase, k2);
        BAR_PLAIN(); MFMAQ(4, 0, af, b0)
        if (more) { BAR_VM4(); } else { BAR_VM0(); }

        // ---- K-tile 1 (buf 1) ----
        LDA4(af, 1, 0) LDB2(b0, 1, 0)
        if (more) STAGE(lds_a, 0, 1, Abase, k2);
        BAR_PLAIN(); MFMAQ(0, 0, af, b0) BAR_PLAIN();

        LDB2(b1, 1, 2)
        if (more) STAGE(lds_b, 0, 1, Bbase, k2);
        BAR_PLAIN(); MFMAQ(0, 2, af, b1) BAR_PLAIN();

        LDA4(af, 1, 4)
        if (more) STAGE(lds_a, 1, 0, Abase, k3);
        BAR_PLAIN(); MFMAQ(4, 2, af, b1) BAR_PLAIN();

        if (more) STAGE(lds_b, 1, 0, Bbase, k3);
        BAR_PLAIN(); MFMAQ(4, 0, af, b0)
        if (more) { BAR_VM4(); } else { BAR_PLAIN(); }
    }

    // epilogue: C/D layout col=lane&15, row=(lane>>4)*4+reg  [verified r2]
    const int lr4 = (lane >> 4) * 4;
#pragma unroll
    for (int mi = 0; mi < 8; ++mi) {
        int rowb = m0 + mi * 32 + wm * 16 + lr4;
#pragma unroll
        for (int ni = 0; ni < 4; ++ni) {
            int col = n0 + ni * 64 + wn * 16 + lrow;
            float bv = bias[col];
#pragma unroll
            for (int r = 0; r < 4; ++r) {
                int row = rowb + r;
                float val = acc[mi][ni][r] + bv;
                if (HAS_GATE) {
                    float g = bf2f(gate[(size_t)row * ldg + col]);
                    val *= g * sigf(g);
                }
                if (OUT_BF16)
                    ((short*)Cv)[(size_t)row * N + col] = f2bf(val);
                else
                    ((float*)Cv)[(size_t)row * N + col] = val;
            }
        }
    }
}

// ---------------- scan pass 1: per-chunk (A = prod oda, Bv = local h, h_init=0) ----------------
__global__ __launch_bounds__(1024) void chunk_reduce(
    const short* __restrict__ pre, float* __restrict__ sA, float* __restrict__ sBv)
{
    const int d = threadIdx.x;
    const int c = blockIdx.x;
    const int b = blockIdx.y;
    float Aacc = 1.f, Bacc = 0.f;
    size_t base = ((size_t)(b * LDIM) + c * LCHUNK) * NPROJ;
    for (int i = 0; i < LCHUNK; ++i) {
        float z  = bf2f(pre[base + d]);
        float dt = bf2f(pre[base + DDIM + d]);
        float e  = __expf(-dt);
        float r  = 1.f / (1.f + e);     // sig(dt)
        float oda = e * r;              // sig(-dt)
        float zda = sigf(z) * r;        // sig(z)*sig(dt)
        Bacc = zda + oda * Bacc;
        Aacc *= oda;
        base += NPROJ;
    }
    int idx = ((b * NCHUNK + c) << 10) + d;
    sA[idx]  = Aacc;
    sBv[idx] = Bacc;
}

// ---------------- scan pass 2: sequential prefix over chunks, record per-chunk h_init ----------------
__global__ __launch_bounds__(1024) void chunk_prefix(
    const float* __restrict__ sA, const float* __restrict__ sBv,
    const float* __restrict__ hidden, float* __restrict__ sI)
{
    const int d = threadIdx.x;
    const int b = blockIdx.x;
    float h = hidden[b * DDIM + d];
    for (int c = 0; c < NCHUNK; ++c) {
        int idx = ((b * NCHUNK + c) << 10) + d;
        sI[idx] = h;
        h = sBv[idx] + sA[idx] * h;
    }
}

// ---------------- scan pass 3: recompute with h_init; write h f32 (d_out) + bf16 (for y-GEMM) ----------------
__global__ __launch_bounds__(1024) void chunk_apply(
    const short* __restrict__ pre, const float* __restrict__ sI,
    float* __restrict__ hout, short* __restrict__ hbf)
{
    const int d = threadIdx.x;
    const int c = blockIdx.x;
    const int b = blockIdx.y;
    float h = sI[((b * NCHUNK + c) << 10) + d];
    size_t base  = ((size_t)(b * LDIM) + c * LCHUNK) * NPROJ;
    size_t obase = ((size_t)(b * LDIM) + c * LCHUNK) * DDIM + d;
    for (int i = 0; i < LCHUNK; ++i) {
        float z  = bf2f(pre[base + d]);
        float dt = bf2f(pre[base + DDIM + d]);
        float e  = __expf(-dt);
        float r  = 1.f / (1.f + e);
        float oda = e * r;
        float zda = sigf(z) * r;
        h = zda + oda * h;
        hout[obase] = h;
        hbf[obase]  = f2bf(h);
        base += NPROJ;
        obase += DDIM;
    }
}

extern "C" void kernel_launch(void* const* d_in, const int* in_sizes, int n_in,
                              void* d_out, int out_size, void* d_ws, size_t ws_size,
                              hipStream_t stream) {
    const float* x      = (const float*)d_in[0];
    const float* hidden = (const float*)d_in[1];
    const float* W_ln_z = (const float*)d_in[2];
    const float* b_ln_z = (const float*)d_in[3];
    const float* W_dt   = (const float*)d_in[4];
    const float* b_dt   = (const float*)d_in[5];
    const float* W_y    = (const float*)d_in[6];
    const float* b_y    = (const float*)d_in[7];
    const float* W_g    = (const float*)d_in[8];
    const float* b_g    = (const float*)d_in[9];

    char* ws = (char*)d_ws;
    // ws layout (bytes)
    short* x_bf   = (short*)(ws + 0);                       // 33,554,432 (reused as h_bf after proj GEMM)
    short* Wcat   = (short*)(ws + 33554432);                //  6,291,456 (W_ln_z|W_dt|W_g)
    short* Wy_bf  = (short*)(ws + 39845888);                //  2,097,152
    float* biascat= (float*)(ws + 41943040);                //     12,288
    short* pre    = (short*)(ws + 41955328);                // 100,663,296 (M x 3072 bf16)
    float* sA     = (float*)(ws + 142618624);               //  1,048,576
    float* sBv    = (float*)(ws + 143667200);               //  1,048,576
    float* sI     = (float*)(ws + 144715776);               //  1,048,576
    // total ~139 MB

    // 1) casts
    cast_f32_bf16<<<2048, 256, 0, stream>>>(x, x_bf, (MROWS * KDIM) / 4);
    cast_f32_bf16<<<1024, 256, 0, stream>>>(W_ln_z, Wcat,                (DDIM * KDIM) / 4);
    cast_f32_bf16<<<1024, 256, 0, stream>>>(W_dt,   Wcat + DDIM * KDIM,  (DDIM * KDIM) / 4);
    cast_f32_bf16<<<1024, 256, 0, stream>>>(W_g,    Wcat + 2 * DDIM * KDIM, (DDIM * KDIM) / 4);
    cast_f32_bf16<<<1024, 256, 0, stream>>>(W_y,    Wy_bf,               (DDIM * KDIM) / 4);

    // 2) concatenated bias (f32)
    hipMemcpyAsync(biascat,            b_ln_z, DDIM * sizeof(float), hipMemcpyDeviceToDevice, stream);
    hipMemcpyAsync(biascat + DDIM,     b_dt,   DDIM * sizeof(float), hipMemcpyDeviceToDevice, stream);
    hipMemcpyAsync(biascat + 2 * DDIM, b_g,    DDIM * sizeof(float), hipMemcpyDeviceToDevice, stream);

    // 3) fused projection GEMM: pre[M x 3072] = x @ [W_ln_z|W_dt|W_g]^T + bias (bf16 out)
    gemm256<1, 0><<<dim3(NPROJ / 256, MROWS / 256), 512, 0, stream>>>(
        x_bf, Wcat, biascat, pre, MROWS, NPROJ, KDIM, nullptr, 0);

    // 4) chunked scan -> h: f32 into d_out second half, bf16 into x_bf (reuse)
    float* y_out = (float*)d_out;
    float* h_out = (float*)d_out + (size_t)MROWS * DDIM;
    short* h_bf  = x_bf;
    chunk_reduce<<<dim3(NCHUNK, BDIM), 1024, 0, stream>>>(pre, sA, sBv);
    chunk_prefix<<<dim3(BDIM), 1024, 0, stream>>>(sA, sBv, hidden, sI);
    chunk_apply<<<dim3(NCHUNK, BDIM), 1024, 0, stream>>>(pre, sI, h_out, h_bf);

    // 5) gated output GEMM (f32 out): y = (h @ W_y^T + b_y) * silu(g_pre)
    gemm256<0, 1><<<dim3(DDIM / 256, MROWS / 256), 512, 0, stream>>>(
        h_bf, Wy_bf, b_y, y_out, MROWS, DDIM, KDIM, pre + 2 * DDIM, NPROJ);
}